// Round 14
// baseline (786.443 us; speedup 1.0000x reference)
//
#include <hip/hip_runtime.h>

// KNN top-16: B=4, N=8192, D=16, k=16, fp32 in, int32 index out.
// FROZEN key model (validated R11-R13, absmax=0): harness np twin =
//   dot  = BLAS microkernel single-accumulator FMA chain, k = 0..15
//   norm = numpy AVX512 pairwise tree: r_j=m_j+m_{j+8}; q_j=r_j+r_{j+4};
//          fl(fl(q0+q2)+fl(q1+q3))
//   val  = fl( fl(ni + fl(-2*dot)) + nj ), ties -> lower index
// Scan and refine use the IDENTICAL key -> per-segment top-16 provably
// contains the global top-16.
// R14 perf: occupancy push. BT=128 (2 waves/block, same segment -> candidate
// pointers stay workgroup-uniform = s_load preserved); S=16 when ws_size
// allows (8192 waves = 32/CU cap) else S=8 fallback; CAP=8 (8 KB LDS/block).

#define B_   4
#define N_   8192
#define D_   16
#define K_   16
#define BT_  128            // scan block threads (2 waves)
#define CAP_ 8              // per-lane LDS append buffer capacity
#define NQ_  (B_ * N_)      // 32768 queries

// numpy AVX512 pairwise-sum tree for 16 contiguous floats. FROZEN.
__device__ __forceinline__ float np_norm16(const float* __restrict__ p) {
#pragma clang fp contract(off)
  float m[16];
#pragma unroll
  for (int d = 0; d < 16; ++d) m[d] = p[d] * p[d];
  float r[8];
#pragma unroll
  for (int j = 0; j < 8; ++j) r[j] = m[j] + m[j + 8];
  float q[4];
#pragma unroll
  for (int j = 0; j < 4; ++j) q[j] = r[j] + r[j + 4];
  return (q[0] + q[2]) + (q[1] + q[3]);
}

// BLAS chain-FMA dot + ordered combine. FROZEN.
__device__ __forceinline__ float np_adj(const float* __restrict__ qa,
                                        const float* __restrict__ cj,
                                        float ni, float nj) {
  float dot = 0.f;
#pragma unroll
  for (int d = 0; d < 16; ++d) dot = __builtin_fmaf(qa[d], cj[d], dot);
  float val;
  {
#pragma clang fp contract(off)
    float inner = -2.0f * dot;   // exact power-of-2 scale
    float u = ni + inner;
    val = u + nj;
  }
  return val;
}

__global__ __launch_bounds__(256) void knn_norms(const float* __restrict__ x,
                                                 float* __restrict__ nrm) {
  int q = blockIdx.x * 256 + threadIdx.x;
  float row[16];
  const float4* xv = (const float4*)(x + (size_t)q * D_);
  float4 a = xv[0], b = xv[1], c = xv[2], d = xv[3];
  row[0]=a.x; row[1]=a.y; row[2]=a.z; row[3]=a.w;
  row[4]=b.x; row[5]=b.y; row[6]=b.z; row[7]=b.w;
  row[8]=c.x; row[9]=c.y; row[10]=c.z; row[11]=c.w;
  row[12]=d.x; row[13]=d.y; row[14]=d.z; row[15]=d.w;
  nrm[q] = np_norm16(row);
}

// ascending insert; '>' keeps earlier (lower idx) on ties
__device__ __forceinline__ void insert16(float d, int j, float (&kd)[K_], int (&ki)[K_]) {
  float cd = d; int ci = j;
#pragma unroll
  for (int p = 0; p < K_; ++p) {
    bool gt = kd[p] > cd;
    float t0 = gt ? cd : kd[p];
    float t1 = gt ? kd[p] : cd;
    int   t2 = gt ? ci : ki[p];
    int   t3 = gt ? ki[p] : ci;
    kd[p] = t0; cd = t1; ki[p] = t2; ci = t3;
  }
}

__device__ __forceinline__ void flushbuf(unsigned long long (*buf)[BT_], int tid,
                                         int& count, float& thr,
                                         float (&kd)[K_], int (&ki)[K_]) {
#pragma unroll 1
  for (int s = 0; s < CAP_; ++s) {
    if (s < count) {
      unsigned long long e = buf[s][tid];
      float d = __uint_as_float((unsigned)(e >> 32));
      if (d < thr) {
        int j = (int)(e & 0xffffu);
        insert16(d, j, kd, ki);
        thr = kd[K_ - 1];
      }
    }
  }
  count = 0;
}

template <int S>
__global__ __launch_bounds__(BT_) void knn_scan(const float* __restrict__ x,
                                                const float* __restrict__ nrm,
                                                unsigned short* __restrict__ pool) {
  constexpr int SEG = N_ / S;
  __shared__ unsigned long long buf[CAP_][BT_];   // [slot][tid]: 2-way aliasing, free
  const int tid = threadIdx.x;
  const int q   = blockIdx.x * BT_ + tid;
  const int seg = blockIdx.y;
  // batch from blockIdx ONLY -> workgroup-uniform -> s_load staging.
  const int bq  = (int)((blockIdx.x * (unsigned)BT_) >> 13);
  const int row0 = bq * N_ + seg * SEG;
  const float* __restrict__ cbase = x + (size_t)row0 * D_;   // SGPR pointer
  const float* __restrict__ nbase = nrm + row0;              // SGPR pointer

  float qa[D_];
  {
    const float4* qv = (const float4*)(x + (size_t)q * D_);
    float4 v0 = qv[0], v1 = qv[1], v2 = qv[2], v3 = qv[3];
    qa[0]=v0.x; qa[1]=v0.y; qa[2]=v0.z; qa[3]=v0.w;
    qa[4]=v1.x; qa[5]=v1.y; qa[6]=v1.z; qa[7]=v1.w;
    qa[8]=v2.x; qa[9]=v2.y; qa[10]=v2.z; qa[11]=v2.w;
    qa[12]=v3.x; qa[13]=v3.y; qa[14]=v3.z; qa[15]=v3.w;
  }
  const float ni = nrm[q];

  float kd[K_]; int ki[K_];
#pragma unroll
  for (int p = 0; p < K_; ++p) { kd[p] = 3.4e38f; ki[p] = 0; }
  float thr = 3.4e38f;
  int count = 0;

#pragma unroll 1
  for (int t = 0; t < SEG; t += 2) {
    // two candidates -> two independent FMA chains; rows stage via s_load
    float c0[D_], c1[D_];
#pragma unroll
    for (int d = 0; d < D_; ++d) c0[d] = cbase[(size_t)t * D_ + d];
#pragma unroll
    for (int d = 0; d < D_; ++d) c1[d] = cbase[(size_t)(t + 1) * D_ + d];
    float nj0 = nbase[t];
    float nj1 = nbase[t + 1];

    float d0 = np_adj(qa, c0, ni, nj0);   // IDENTICAL key to refine
    float d1 = np_adj(qa, c1, ni, nj1);

    if (d0 < thr) {
      buf[count][tid] = ((unsigned long long)__float_as_uint(d0) << 32) | (unsigned)t;
      ++count;
    }
    if (d1 < thr) {
      buf[count][tid] = ((unsigned long long)__float_as_uint(d1) << 32) | (unsigned)(t + 1);
      ++count;
    }
    if (__any(count >= CAP_ - 1)) flushbuf(buf, tid, count, thr, kd, ki);
  }
  flushbuf(buf, tid, count, thr, kd, ki);

  unsigned* pp = (unsigned*)(pool + ((size_t)q * S + seg) * K_);
#pragma unroll
  for (int p = 0; p < K_ / 2; ++p) {
    unsigned lo = (unsigned)(seg * SEG + ki[2 * p]);
    unsigned hi = (unsigned)(seg * SEG + ki[2 * p + 1]);
    pp[p] = lo | (hi << 16);
  }
}

template <int S>
__global__ __launch_bounds__(256) void knn_refine(const float* __restrict__ x,
                                                  const float* __restrict__ nrm,
                                                  const unsigned short* __restrict__ pool,
                                                  int* __restrict__ out) {
  constexpr int POOL = S * K_;       // 128 or 256
  constexpr int SL   = POOL / 64;    // slots per lane: 2 or 4
  const int tid  = threadIdx.x;
  const int lane = tid & 63;
  const int q    = blockIdx.x * 4 + (tid >> 6);  // one wave per query
  const int b    = q >> 13;
  const unsigned short* __restrict__ pp = pool + (size_t)q * POOL;

  float qa[D_];
  {
    const float4* qv = (const float4*)(x + (size_t)q * D_);
    float4 v0 = qv[0], v1 = qv[1], v2 = qv[2], v3 = qv[3];
    qa[0]=v0.x; qa[1]=v0.y; qa[2]=v0.z; qa[3]=v0.w;
    qa[4]=v1.x; qa[5]=v1.y; qa[6]=v1.z; qa[7]=v1.w;
    qa[8]=v2.x; qa[9]=v2.y; qa[10]=v2.z; qa[11]=v2.w;
    qa[12]=v3.x; qa[13]=v3.y; qa[14]=v3.z; qa[15]=v3.w;
  }
  const float ni = nrm[q];

  int   jj[SL];
  float vv[SL];
#pragma unroll
  for (int s = 0; s < SL; ++s) {
    int j = (int)pp[lane + 64 * s];
    jj[s] = j;
    float cj[D_];
    const float4* cv = (const float4*)(x + ((size_t)(b * N_) + j) * D_);
    float4 a = cv[0], bb = cv[1], c = cv[2], d = cv[3];
    cj[0]=a.x; cj[1]=a.y; cj[2]=a.z; cj[3]=a.w;
    cj[4]=bb.x; cj[5]=bb.y; cj[6]=bb.z; cj[7]=bb.w;
    cj[8]=c.x; cj[9]=c.y; cj[10]=c.z; cj[11]=c.w;
    cj[12]=d.x; cj[13]=d.y; cj[14]=d.z; cj[15]=d.w;
    vv[s] = np_adj(qa, cj, ni, nrm[b * N_ + j]);   // bit-identical to scan
  }

  // exact rank among all POOL slots by (np-key asc, index asc)
  int rr[SL];
#pragma unroll
  for (int s = 0; s < SL; ++s) rr[s] = 0;
  for (int t = 0; t < 64; ++t) {
#pragma unroll
    for (int a = 0; a < SL; ++a) {
      float va = __shfl(vv[a], t);
      int   ja = __shfl(jj[a], t);
#pragma unroll
      for (int s = 0; s < SL; ++s)
        rr[s] += (va < vv[s] || (va == vv[s] && ja < jj[s])) ? 1 : 0;
    }
  }
#pragma unroll
  for (int s = 0; s < SL; ++s)
    if (rr[s] < K_) out[(size_t)q * K_ + rr[s]] = jj[s];
}

extern "C" void kernel_launch(void* const* d_in, const int* in_sizes, int n_in,
                              void* d_out, int out_size, void* d_ws, size_t ws_size,
                              hipStream_t stream) {
  const float* x = (const float*)d_in[0];
  float* nrm = (float*)d_ws;                                          // 128 KB
  unsigned short* pool = (unsigned short*)((char*)d_ws + 256 * 1024);
  int* out = (int*)d_out;

  knn_norms<<<NQ_ / 256, 256, 0, stream>>>(x, nrm);

  const size_t need16 = 256 * 1024 + (size_t)NQ_ * 16 * K_ * 2;  // ~17 MB
  if (ws_size >= need16) {
    dim3 g2(NQ_ / BT_, 16);
    knn_scan<16><<<g2, BT_, 0, stream>>>(x, nrm, pool);
    knn_refine<16><<<NQ_ / 4, 256, 0, stream>>>(x, nrm, pool, out);
  } else {
    dim3 g2(NQ_ / BT_, 8);
    knn_scan<8><<<g2, BT_, 0, stream>>>(x, nrm, pool);
    knn_refine<8><<<NQ_ / 4, 256, 0, stream>>>(x, nrm, pool, out);
  }
}

// Round 15
// 658.117 us; speedup vs baseline: 1.1950x; 1.1950x over previous
//
#include <hip/hip_runtime.h>

// KNN top-16: B=4, N=8192, D=16, k=16, fp32 in, int32 index out.
// FROZEN key model (validated R11-R14, absmax=0): harness np twin =
//   dot  = BLAS microkernel single-accumulator FMA chain, k = 0..15
//   norm = numpy AVX512 pairwise tree: r_j=m_j+m_{j+8}; q_j=r_j+r_{j+4};
//          fl(fl(q0+q2)+fl(q1+q3))
//   val  = fl( fl(ni + fl(-2*dot)) + nj ), ties -> lower index
// R15: scan stores packed u64 (monotone(key)<<32 | idx) -> refine is a pure
// u64 rank (no recompute, no gathers). u64 order == (key asc, idx asc).
// ws-adaptive: S=16 u64 pool (64.25MB) / S=8 u64 (32.25MB) / u16 fallback.

#define B_   4
#define N_   8192
#define D_   16
#define K_   16
#define BT_  128            // scan block threads (2 waves)
#define CAP_ 8              // per-lane LDS append buffer capacity
#define NQ_  (B_ * N_)      // 32768 queries

typedef unsigned long long u64;

// numpy AVX512 pairwise-sum tree for 16 contiguous floats. FROZEN.
__device__ __forceinline__ float np_norm16(const float* __restrict__ p) {
#pragma clang fp contract(off)
  float m[16];
#pragma unroll
  for (int d = 0; d < 16; ++d) m[d] = p[d] * p[d];
  float r[8];
#pragma unroll
  for (int j = 0; j < 8; ++j) r[j] = m[j] + m[j + 8];
  float q[4];
#pragma unroll
  for (int j = 0; j < 4; ++j) q[j] = r[j] + r[j + 4];
  return (q[0] + q[2]) + (q[1] + q[3]);
}

// monotone fp32->u32: uint ascending == float ascending (handles negatives)
__device__ __forceinline__ unsigned mono32(float f) {
  unsigned u = __float_as_uint(f);
  return u ^ ((unsigned)((int)u >> 31) | 0x80000000u);
}

__global__ __launch_bounds__(256) void knn_norms(const float* __restrict__ x,
                                                 float* __restrict__ nrm) {
  int q = blockIdx.x * 256 + threadIdx.x;
  float row[16];
  const float4* xv = (const float4*)(x + (size_t)q * D_);
  float4 a = xv[0], b = xv[1], c = xv[2], d = xv[3];
  row[0]=a.x; row[1]=a.y; row[2]=a.z; row[3]=a.w;
  row[4]=b.x; row[5]=b.y; row[6]=b.z; row[7]=b.w;
  row[8]=c.x; row[9]=c.y; row[10]=c.z; row[11]=c.w;
  row[12]=d.x; row[13]=d.y; row[14]=d.z; row[15]=d.w;
  nrm[q] = np_norm16(row);
}

// ascending insert; '>' keeps earlier (lower idx) on ties
__device__ __forceinline__ void insert16(float d, int j, float (&kd)[K_], int (&ki)[K_]) {
  float cd = d; int ci = j;
#pragma unroll
  for (int p = 0; p < K_; ++p) {
    bool gt = kd[p] > cd;
    float t0 = gt ? cd : kd[p];
    float t1 = gt ? kd[p] : cd;
    int   t2 = gt ? ci : ki[p];
    int   t3 = gt ? ki[p] : ci;
    kd[p] = t0; cd = t1; ki[p] = t2; ci = t3;
  }
}

__device__ __forceinline__ void flushbuf(u64 (*buf)[BT_], int tid,
                                         int& count, float& thr,
                                         float (&kd)[K_], int (&ki)[K_]) {
#pragma unroll 1
  for (int s = 0; s < CAP_; ++s) {
    if (s < count) {
      u64 e = buf[s][tid];
      float d = __uint_as_float((unsigned)(e >> 32));
      if (d < thr) {
        int j = (int)(e & 0xffffu);
        insert16(d, j, kd, ki);
        thr = kd[K_ - 1];
      }
    }
  }
  count = 0;
}

// Core scan: per-(query,segment) np-exact top-16. Emit<WriteU64> selects pool
// format: u64 (mono key | idx) or u16 (idx only, fallback path).
template <int S, bool WRITE64>
__global__ __launch_bounds__(BT_) void knn_scan(const float* __restrict__ x,
                                                const float* __restrict__ nrm,
                                                void* __restrict__ pool) {
  constexpr int SEG = N_ / S;
  __shared__ u64 buf[CAP_][BT_];
  const int tid = threadIdx.x;
  const int q   = blockIdx.x * BT_ + tid;
  const int seg = blockIdx.y;
  // batch from blockIdx ONLY -> workgroup-uniform -> s_load staging.
  const int bq  = (int)((blockIdx.x * (unsigned)BT_) >> 13);
  const int row0 = bq * N_ + seg * SEG;
  const float* __restrict__ cbase = x + (size_t)row0 * D_;   // SGPR pointer
  const float* __restrict__ nbase = nrm + row0;              // SGPR pointer

  float qa[D_];
  {
    const float4* qv = (const float4*)(x + (size_t)q * D_);
    float4 v0 = qv[0], v1 = qv[1], v2 = qv[2], v3 = qv[3];
    qa[0]=v0.x; qa[1]=v0.y; qa[2]=v0.z; qa[3]=v0.w;
    qa[4]=v1.x; qa[5]=v1.y; qa[6]=v1.z; qa[7]=v1.w;
    qa[8]=v2.x; qa[9]=v2.y; qa[10]=v2.z; qa[11]=v2.w;
    qa[12]=v3.x; qa[13]=v3.y; qa[14]=v3.z; qa[15]=v3.w;
  }
  const float ni = nrm[q];

  float kd[K_]; int ki[K_];
#pragma unroll
  for (int p = 0; p < K_; ++p) { kd[p] = 3.4e38f; ki[p] = 0; }
  float thr = 3.4e38f;
  int count = 0;

#pragma unroll 1
  for (int t = 0; t < SEG; t += 2) {
    float c0[D_], c1[D_];
#pragma unroll
    for (int d = 0; d < D_; ++d) c0[d] = cbase[(size_t)t * D_ + d];
#pragma unroll
    for (int d = 0; d < D_; ++d) c1[d] = cbase[(size_t)(t + 1) * D_ + d];
    float nj0 = nbase[t];
    float nj1 = nbase[t + 1];

    // two independent np-exact FMA chains, interleaved (SLP -> v_pk_fma_f32)
    float dot0 = 0.f, dot1 = 0.f;
#pragma unroll
    for (int d = 0; d < D_; ++d) {
      dot0 = __builtin_fmaf(qa[d], c0[d], dot0);
      dot1 = __builtin_fmaf(qa[d], c1[d], dot1);
    }
    float d0, d1;
    {
#pragma clang fp contract(off)
      float i0 = -2.0f * dot0;  float i1 = -2.0f * dot1;
      float u0 = ni + i0;       float u1 = ni + i1;
      d0 = u0 + nj0;            d1 = u1 + nj1;
    }

    if (d0 < thr) {
      buf[count][tid] = ((u64)__float_as_uint(d0) << 32) | (unsigned)t;
      ++count;
    }
    if (d1 < thr) {
      buf[count][tid] = ((u64)__float_as_uint(d1) << 32) | (unsigned)(t + 1);
      ++count;
    }
    if (__any(count >= CAP_ - 1)) flushbuf(buf, tid, count, thr, kd, ki);
  }
  flushbuf(buf, tid, count, thr, kd, ki);

  if (WRITE64) {
    u64* pp = (u64*)pool + ((size_t)q * S + seg) * K_;
#pragma unroll
    for (int p = 0; p < K_; ++p) {
      unsigned gj = (unsigned)(seg * SEG + ki[p]);
      pp[p] = ((u64)mono32(kd[p]) << 32) | gj;
    }
  } else {
    unsigned* pp = (unsigned*)((unsigned short*)pool + ((size_t)q * S + seg) * K_);
#pragma unroll
    for (int p = 0; p < K_ / 2; ++p) {
      unsigned lo = (unsigned)(seg * SEG + ki[2 * p]);
      unsigned hi = (unsigned)(seg * SEG + ki[2 * p + 1]);
      pp[p] = lo | (hi << 16);
    }
  }
}

// u64-pool refine: pure rank of stored keys. u64 asc == (key asc, idx asc).
template <int S>
__global__ __launch_bounds__(256) void knn_refine64(const u64* __restrict__ pool,
                                                    int* __restrict__ out) {
  constexpr int POOL = S * K_;       // 128 or 256
  constexpr int SL   = POOL / 64;    // 2 or 4 slots per lane
  const int tid  = threadIdx.x;
  const int lane = tid & 63;
  const int q    = blockIdx.x * 4 + (tid >> 6);  // one wave per query
  const u64* __restrict__ pp = pool + (size_t)q * POOL;

  u64 e[SL];
#pragma unroll
  for (int s = 0; s < SL; ++s) e[s] = pp[lane + 64 * s];

  int rr[SL];
#pragma unroll
  for (int s = 0; s < SL; ++s) rr[s] = 0;
  for (int t = 0; t < 64; ++t) {
#pragma unroll
    for (int a = 0; a < SL; ++a) {
      u64 ea = __shfl(e[a], t);
#pragma unroll
      for (int s = 0; s < SL; ++s) rr[s] += (ea < e[s]) ? 1 : 0;
    }
  }
#pragma unroll
  for (int s = 0; s < SL; ++s)
    if (rr[s] < K_) out[(size_t)q * K_ + rr[s]] = (int)(e[s] & 0xffffu);
}

// Fallback refine (u16 idx pool): recompute np-exact key (R13/R14-proven).
__device__ __forceinline__ float np_adj1(const float* __restrict__ qa,
                                         const float* __restrict__ cj,
                                         float ni, float nj) {
  float dot = 0.f;
#pragma unroll
  for (int d = 0; d < 16; ++d) dot = __builtin_fmaf(qa[d], cj[d], dot);
  float val;
  {
#pragma clang fp contract(off)
    float inner = -2.0f * dot;
    float u = ni + inner;
    val = u + nj;
  }
  return val;
}

template <int S>
__global__ __launch_bounds__(256) void knn_refine16(const float* __restrict__ x,
                                                    const float* __restrict__ nrm,
                                                    const unsigned short* __restrict__ pool,
                                                    int* __restrict__ out) {
  constexpr int POOL = S * K_;
  constexpr int SL   = POOL / 64;
  const int tid  = threadIdx.x;
  const int lane = tid & 63;
  const int q    = blockIdx.x * 4 + (tid >> 6);
  const int b    = q >> 13;
  const unsigned short* __restrict__ pp = pool + (size_t)q * POOL;

  float qa[D_];
  {
    const float4* qv = (const float4*)(x + (size_t)q * D_);
    float4 v0 = qv[0], v1 = qv[1], v2 = qv[2], v3 = qv[3];
    qa[0]=v0.x; qa[1]=v0.y; qa[2]=v0.z; qa[3]=v0.w;
    qa[4]=v1.x; qa[5]=v1.y; qa[6]=v1.z; qa[7]=v1.w;
    qa[8]=v2.x; qa[9]=v2.y; qa[10]=v2.z; qa[11]=v2.w;
    qa[12]=v3.x; qa[13]=v3.y; qa[14]=v3.z; qa[15]=v3.w;
  }
  const float ni = nrm[q];

  int   jj[SL];
  float vv[SL];
#pragma unroll
  for (int s = 0; s < SL; ++s) {
    int j = (int)pp[lane + 64 * s];
    jj[s] = j;
    float cj[D_];
    const float4* cv = (const float4*)(x + ((size_t)(b * N_) + j) * D_);
    float4 a = cv[0], bb = cv[1], c = cv[2], d = cv[3];
    cj[0]=a.x; cj[1]=a.y; cj[2]=a.z; cj[3]=a.w;
    cj[4]=bb.x; cj[5]=bb.y; cj[6]=bb.z; cj[7]=bb.w;
    cj[8]=c.x; cj[9]=c.y; cj[10]=c.z; cj[11]=c.w;
    cj[12]=d.x; cj[13]=d.y; cj[14]=d.z; cj[15]=d.w;
    vv[s] = np_adj1(qa, cj, ni, nrm[b * N_ + j]);
  }
  int rr[SL];
#pragma unroll
  for (int s = 0; s < SL; ++s) rr[s] = 0;
  for (int t = 0; t < 64; ++t) {
#pragma unroll
    for (int a = 0; a < SL; ++a) {
      float va = __shfl(vv[a], t);
      int   ja = __shfl(jj[a], t);
#pragma unroll
      for (int s = 0; s < SL; ++s)
        rr[s] += (va < vv[s] || (va == vv[s] && ja < jj[s])) ? 1 : 0;
    }
  }
#pragma unroll
  for (int s = 0; s < SL; ++s)
    if (rr[s] < K_) out[(size_t)q * K_ + rr[s]] = jj[s];
}

extern "C" void kernel_launch(void* const* d_in, const int* in_sizes, int n_in,
                              void* d_out, int out_size, void* d_ws, size_t ws_size,
                              hipStream_t stream) {
  const float* x = (const float*)d_in[0];
  float* nrm = (float*)d_ws;                         // 128 KB used of 256 KB
  void* pool = (void*)((char*)d_ws + 256 * 1024);
  int* out = (int*)d_out;

  knn_norms<<<NQ_ / 256, 256, 0, stream>>>(x, nrm);

  const size_t base = 256 * 1024;
  const size_t need16_64 = base + (size_t)NQ_ * 16 * K_ * 8;  // 64.25 MB
  const size_t need8_64  = base + (size_t)NQ_ * 8  * K_ * 8;  // 32.25 MB

  if (ws_size >= need16_64) {
    dim3 g2(NQ_ / BT_, 16);
    knn_scan<16, true><<<g2, BT_, 0, stream>>>(x, nrm, pool);
    knn_refine64<16><<<NQ_ / 4, 256, 0, stream>>>((const u64*)pool, out);
  } else if (ws_size >= need8_64) {
    dim3 g2(NQ_ / BT_, 8);
    knn_scan<8, true><<<g2, BT_, 0, stream>>>(x, nrm, pool);
    knn_refine64<8><<<NQ_ / 4, 256, 0, stream>>>((const u64*)pool, out);
  } else {
    dim3 g2(NQ_ / BT_, 8);
    knn_scan<8, false><<<g2, BT_, 0, stream>>>(x, nrm, pool);
    knn_refine16<8><<<NQ_ / 4, 256, 0, stream>>>(x, nrm,
                                                 (const unsigned short*)pool, out);
  }
}